// Round 11
// baseline (326.396 us; speedup 1.0000x reference)
//
#include <hip/hip_runtime.h>
#include <hip/hip_bf16.h>

#define TTT_LR 0.01f
#define LN_EPS 1e-5f

// Problem dims (fixed by reference)
#define BB 4
#define SS 2048
#define DD 1024
#define DSZ 64
#define CHUNK 64
#define NC (SS / CHUNK)   // 32
#define NCAT 1152         // 64 k + 64 q + 1024 v output cols
#define NCVT (NCAT * DD / 4 / 256)   // 1152 cvt blocks
#define MiB (1024ull * 1024ull)

typedef __hip_bfloat16 bf16;
typedef __bf16 bf16x8 __attribute__((ext_vector_type(8)));
typedef float f32x4 __attribute__((ext_vector_type(4)));

__device__ __forceinline__ void gload_lds16(const void* g, void* l) {
    __builtin_amdgcn_global_load_lds(
        (const __attribute__((address_space(1))) unsigned int*)g,
        (__attribute__((address_space(3))) unsigned int*)l, 16, 0, 0);
}

// ---------------------------------------------------------------------------
// Kernel 1: merged pre-pass. Blocks [0,NCVT): Wk/Wq/Wv -> bf16 Wcat.
// Blocks [NCVT, NCVT+B*S): LayerNorm row -> h (bf16).
// ---------------------------------------------------------------------------
__global__ __launch_bounds__(256) void pre_kernel(
    const float* __restrict__ Wk, const float* __restrict__ Wq,
    const float* __restrict__ Wv, bf16* __restrict__ Wcat,
    const float* __restrict__ x, const float* __restrict__ gamma,
    const float* __restrict__ beta, bf16* __restrict__ hb)
{
    __shared__ float wsum[4], wsum2[4];
    const int tid = threadIdx.x;

    if (blockIdx.x < NCVT) {
        const int i = blockIdx.x * 256 + tid;           // float4 group index
        const int idx = i * 4;
        const int row = idx >> 10, col = idx & 1023;
        const float* src = (row < 64)  ? (Wk + (size_t)row * DD)
                         : (row < 128) ? (Wq + (size_t)(row - 64) * DD)
                                       : (Wv + (size_t)(row - 128) * DD);
        float4 v = *reinterpret_cast<const float4*>(src + col);
        bf16 h4[4] = {__float2bfloat16(v.x), __float2bfloat16(v.y),
                      __float2bfloat16(v.z), __float2bfloat16(v.w)};
        *reinterpret_cast<ushort4*>(Wcat + idx) = *reinterpret_cast<ushort4*>(h4);
        return;
    }

    const int row = blockIdx.x - NCVT;
    const int lane = tid & 63, wave = tid >> 6;

    float4 v0 = *reinterpret_cast<const float4*>(x + (size_t)row * DD + tid * 4);
    float s = v0.x + v0.y + v0.z + v0.w;
    float s2 = fmaf(v0.x, v0.x, fmaf(v0.y, v0.y, fmaf(v0.z, v0.z, v0.w * v0.w)));
    #pragma unroll
    for (int off = 32; off > 0; off >>= 1) {
        s  += __shfl_down(s, off, 64);
        s2 += __shfl_down(s2, off, 64);
    }
    if (lane == 0) { wsum[wave] = s; wsum2[wave] = s2; }
    __syncthreads();
    s  = wsum[0] + wsum[1] + wsum[2] + wsum[3];
    s2 = wsum2[0] + wsum2[1] + wsum2[2] + wsum2[3];
    const float mu = s * (1.0f / DD);
    const float rs = rsqrtf(s2 * (1.0f / DD) - mu * mu + LN_EPS);

    float4 g  = *reinterpret_cast<const float4*>(gamma + tid * 4);
    float4 be = *reinterpret_cast<const float4*>(beta + tid * 4);
    bf16 h4[4];
    h4[0] = __float2bfloat16((v0.x - mu) * rs * g.x + be.x);
    h4[1] = __float2bfloat16((v0.y - mu) * rs * g.y + be.y);
    h4[2] = __float2bfloat16((v0.z - mu) * rs * g.z + be.z);
    h4[3] = __float2bfloat16((v0.w - mu) * rs * g.w + be.w);
    *reinterpret_cast<ushort4*>(hb + (size_t)row * DD + tid * 4) =
        *reinterpret_cast<ushort4*>(h4);
}

// ---------------------------------------------------------------------------
// Kernel 2: fused kqv = h @ Wcat^T + bias. 128x128 tile, BK=64,
// global_load_lds(16B) staging, XOR-swizzled 16B blocks. 1D grid with
// XCD-aware mapping: xcd = bid&7 owns m-groups [8*xcd, 8*xcd+8); the 9
// blocks sharing an h-slab run consecutively on ONE XCD (h slab 256 KB +
// Wcat 2.25 MB stay L2-resident).
// ---------------------------------------------------------------------------
__global__ __launch_bounds__(256) void kqv_kernel(
    const bf16* __restrict__ h, const bf16* __restrict__ Wcat,
    const float* __restrict__ bk, const float* __restrict__ bq,
    const float* __restrict__ bv,
    float* __restrict__ kbuf, float* __restrict__ qbuf, bf16* __restrict__ vbuf16)
{
    __shared__ bf16 Ash[128 * 64];
    __shared__ bf16 Bsh[128 * 64];
    const int tid = threadIdx.x, lane = tid & 63, wave = tid >> 6;
    const int m = lane & 15, quad = lane >> 4;
    const int wr = wave >> 1, wc = wave & 1;

    // XCD-aware decode: 576 blocks = 8 XCDs x 72 slots (8 m-groups x 9 n)
    const int bid = blockIdx.x;
    const int xcd = bid & 7, slot = bid >> 3;
    const int m_idx = xcd * 8 + slot / 9;       // 0..63
    const int n_idx = slot % 9;                 // 0..8
    const int m0 = m_idx * 128;                 // h rows
    const int n0 = n_idx * 128;                 // Wcat rows

    const int srow = wave * 8 + (lane >> 3);   // staging row (+ i*32)
    const int scb = lane & 7;                  // staging 16B-block in row

    f32x4 acc[4][4] = {};

    for (int k0 = 0; k0 < DD; k0 += 64) {
        __syncthreads();                       // prior frag reads done
        #pragma unroll
        for (int i = 0; i < 4; ++i) {
            const int row = i * 32 + srow;
            const int g16 = scb ^ (row & 7);   // swizzled source block
            gload_lds16(h    + (size_t)(m0 + row) * DD + k0 + g16 * 8,
                        (char*)Ash + (size_t)(i * 32 + wave * 8) * 128);
            gload_lds16(Wcat + (size_t)(n0 + row) * DD + k0 + g16 * 8,
                        (char*)Bsh + (size_t)(i * 32 + wave * 8) * 128);
        }
        __syncthreads();                       // DMA drained (vmcnt0 @ barrier)
        #pragma unroll
        for (int ks = 0; ks < 2; ++ks) {
            bf16x8 af[4], bfr[4];
            #pragma unroll
            for (int mt = 0; mt < 4; ++mt) {
                const int row = wr * 64 + mt * 16 + m;
                const int kb = (ks * 4 + quad) ^ (row & 7);
                af[mt] = *reinterpret_cast<const bf16x8*>(&Ash[row * 64 + kb * 8]);
            }
            #pragma unroll
            for (int nt = 0; nt < 4; ++nt) {
                const int row = wc * 64 + nt * 16 + m;
                const int kb = (ks * 4 + quad) ^ (row & 7);
                bfr[nt] = *reinterpret_cast<const bf16x8*>(&Bsh[row * 64 + kb * 8]);
            }
            #pragma unroll
            for (int mt = 0; mt < 4; ++mt)
                #pragma unroll
                for (int nt = 0; nt < 4; ++nt)
                    acc[mt][nt] = __builtin_amdgcn_mfma_f32_16x16x32_bf16(
                        af[mt], bfr[nt], acc[mt][nt], 0, 0, 0);
        }
    }

    #pragma unroll
    for (int nt = 0; nt < 4; ++nt) {
        const int n = n0 + wc * 64 + nt * 16 + m;
        if (n < 64) {
            const float bias = bk[n];
            #pragma unroll
            for (int mt = 0; mt < 4; ++mt) {
                const int row = m0 + wr * 64 + mt * 16 + quad * 4;
                #pragma unroll
                for (int r = 0; r < 4; ++r)
                    kbuf[(size_t)(row + r) * DSZ + n] = acc[mt][nt][r] + bias;
            }
        } else if (n < 128) {
            const float bias = bq[n - 64];
            #pragma unroll
            for (int mt = 0; mt < 4; ++mt) {
                const int row = m0 + wr * 64 + mt * 16 + quad * 4;
                #pragma unroll
                for (int r = 0; r < 4; ++r)
                    qbuf[(size_t)(row + r) * DSZ + (n - 64)] = acc[mt][nt][r] + bias;
            }
        } else {
            const float bias = bv[n - 128];
            #pragma unroll
            for (int mt = 0; mt < 4; ++mt) {
                const int row = m0 + wr * 64 + mt * 16 + quad * 4;
                #pragma unroll
                for (int r = 0; r < 4; ++r)
                    vbuf16[(size_t)(row + r) * DD + (n - 128)] =
                        __float2bfloat16(acc[mt][nt][r] + bias);
            }
        }
    }
}

// ---------------------------------------------------------------------------
// Kernel 3: per-(b,chunk) prep — MFMA (unchanged). 4 chunk matrices (bf16):
//   Qtb16 = Q - Astl*B (rows t) ; AMb16 = Astl*(lr*Minv) (rows t)
//   Tb16 = -K^T B (rows s)      ; Wb16 = K^T (lr*Minv) (rows s)
// ---------------------------------------------------------------------------
__global__ __launch_bounds__(256) void prep_kernel(
    const float* __restrict__ kbuf, const float* __restrict__ qbuf,
    bf16* __restrict__ Tb16, bf16* __restrict__ Wb16,
    bf16* __restrict__ AMb16, bf16* __restrict__ Qtb16)
{
    __shared__ bf16 K16[64 * 72];
    __shared__ bf16 Kt16[64 * 72];
    __shared__ bf16 Q16[64 * 72];
    __shared__ bf16 Astl[64 * 72];
    __shared__ bf16 Minv16[64 * 72];
    __shared__ bf16 MinvT16[64 * 72];
    __shared__ bf16 BnegT[64 * 72];
    __shared__ float Gf[64 * 65];
    __shared__ float Mf[64 * 65];

    const int c = blockIdx.x, b = blockIdx.y;
    const int tid = threadIdx.x, lane = tid & 63, w = tid >> 6;
    const int m = lane & 15, quad = lane >> 4;
    const float* kp = kbuf + ((size_t)b * SS + c * 64) * DSZ;
    const float* qp = qbuf + ((size_t)b * SS + c * 64) * DSZ;
    const size_t cb = ((size_t)b * NC + c) * 4096;

    #pragma unroll
    for (int it = 0; it < 4; ++it) {
        const int f4 = tid + it * 256;
        const int t = f4 >> 4;
        const int s = (f4 & 15) * 4;
        float4 kv = *reinterpret_cast<const float4*>(kp + t * DSZ + s);
        float4 qv = *reinterpret_cast<const float4*>(qp + t * DSZ + s);
        bf16 kb4[4] = {__float2bfloat16(kv.x), __float2bfloat16(kv.y),
                       __float2bfloat16(kv.z), __float2bfloat16(kv.w)};
        bf16 qb4[4] = {__float2bfloat16(qv.x), __float2bfloat16(qv.y),
                       __float2bfloat16(qv.z), __float2bfloat16(qv.w)};
        *reinterpret_cast<ushort4*>(&K16[t * 72 + s]) = *reinterpret_cast<ushort4*>(kb4);
        *reinterpret_cast<ushort4*>(&Q16[t * 72 + s]) = *reinterpret_cast<ushort4*>(qb4);
        #pragma unroll
        for (int i = 0; i < 4; ++i) Kt16[(s + i) * 72 + t] = kb4[i];
    }
    __syncthreads();

    bf16x8 afK[2], afQ[2], bfK[4][2];
    #pragma unroll
    for (int ks = 0; ks < 2; ++ks) {
        afK[ks] = *reinterpret_cast<const bf16x8*>(&K16[(w * 16 + m) * 72 + ks * 32 + quad * 8]);
        afQ[ks] = *reinterpret_cast<const bf16x8*>(&Q16[(w * 16 + m) * 72 + ks * 32 + quad * 8]);
        #pragma unroll
        for (int nt = 0; nt < 4; ++nt)
            bfK[nt][ks] = *reinterpret_cast<const bf16x8*>(&K16[(nt * 16 + m) * 72 + ks * 32 + quad * 8]);
    }
    f32x4 gacc[4] = {}, aacc[4] = {};
    #pragma unroll
    for (int ks = 0; ks < 2; ++ks)
        #pragma unroll
        for (int nt = 0; nt < 4; ++nt) {
            gacc[nt] = __builtin_amdgcn_mfma_f32_16x16x32_bf16(afK[ks], bfK[nt][ks], gacc[nt], 0, 0, 0);
            aacc[nt] = __builtin_amdgcn_mfma_f32_16x16x32_bf16(afQ[ks], bfK[nt][ks], aacc[nt], 0, 0, 0);
        }
    #pragma unroll
    for (int nt = 0; nt < 4; ++nt)
        #pragma unroll
        for (int r = 0; r < 4; ++r) {
            const int t = w * 16 + quad * 4 + r, j = nt * 16 + m;
            Gf[t * 65 + j] = TTT_LR * gacc[nt][r];
            Astl[t * 72 + j] = __float2bfloat16(j < t ? aacc[nt][r] : 0.f);
        }
    __syncthreads();

    if (tid < 64) {
        for (int t = 0; t < 64; ++t) {
            float acc = (t == tid) ? 1.f : 0.f;
            for (int i = 0; i < t; ++i)
                acc = fmaf(-Gf[t * 65 + i], Mf[i * 65 + tid], acc);
            Mf[t * 65 + tid] = acc;
        }
    }
    __syncthreads();

    #pragma unroll
    for (int it = 0; it < 16; ++it) {
        const int e = tid + it * 256;
        const int t = e >> 6, j = e & 63;
        const bf16 vb = __float2bfloat16(TTT_LR * Mf[t * 65 + j]);
        Minv16[t * 72 + j] = vb;
        MinvT16[j * 72 + t] = vb;
    }
    __syncthreads();

    bf16x8 afM[2], afA[2], afKt[2], bfKt[4][2], bfMt[4][2];
    #pragma unroll
    for (int ks = 0; ks < 2; ++ks) {
        afM[ks]  = *reinterpret_cast<const bf16x8*>(&Minv16[(w * 16 + m) * 72 + ks * 32 + quad * 8]);
        afA[ks]  = *reinterpret_cast<const bf16x8*>(&Astl[(w * 16 + m) * 72 + ks * 32 + quad * 8]);
        afKt[ks] = *reinterpret_cast<const bf16x8*>(&Kt16[(w * 16 + m) * 72 + ks * 32 + quad * 8]);
        #pragma unroll
        for (int nt = 0; nt < 4; ++nt) {
            bfKt[nt][ks] = *reinterpret_cast<const bf16x8*>(&Kt16[(nt * 16 + m) * 72 + ks * 32 + quad * 8]);
            bfMt[nt][ks] = *reinterpret_cast<const bf16x8*>(&MinvT16[(nt * 16 + m) * 72 + ks * 32 + quad * 8]);
        }
    }
    f32x4 bacc[4] = {};
    #pragma unroll
    for (int ks = 0; ks < 2; ++ks)
        #pragma unroll
        for (int nt = 0; nt < 4; ++nt)
            bacc[nt] = __builtin_amdgcn_mfma_f32_16x16x32_bf16(afM[ks], bfKt[nt][ks], bacc[nt], 0, 0, 0);
    #pragma unroll
    for (int nt = 0; nt < 4; ++nt)
        #pragma unroll
        for (int r = 0; r < 4; ++r) {
            const int t = w * 16 + quad * 4 + r, s = nt * 16 + m;
            BnegT[s * 72 + t] = __float2bfloat16(-bacc[nt][r]);
        }
    __syncthreads();

    f32x4 qtacc[4], amacc[4] = {}, tacc[4] = {}, wacc[4] = {};
    #pragma unroll
    for (int nt = 0; nt < 4; ++nt)
        #pragma unroll
        for (int r = 0; r < 4; ++r)
            qtacc[nt][r] = qp[(w * 16 + quad * 4 + r) * DSZ + nt * 16 + m];
    #pragma unroll
    for (int ks = 0; ks < 2; ++ks)
        #pragma unroll
        for (int nt = 0; nt < 4; ++nt) {
            const bf16x8 bfBn = *reinterpret_cast<const bf16x8*>(
                &BnegT[(nt * 16 + m) * 72 + ks * 32 + quad * 8]);
            qtacc[nt] = __builtin_amdgcn_mfma_f32_16x16x32_bf16(afA[ks], bfBn, qtacc[nt], 0, 0, 0);
            amacc[nt] = __builtin_amdgcn_mfma_f32_16x16x32_bf16(afA[ks], bfMt[nt][ks], amacc[nt], 0, 0, 0);
            tacc[nt]  = __builtin_amdgcn_mfma_f32_16x16x32_bf16(afKt[ks], bfBn, tacc[nt], 0, 0, 0);
            wacc[nt]  = __builtin_amdgcn_mfma_f32_16x16x32_bf16(afKt[ks], bfMt[nt][ks], wacc[nt], 0, 0, 0);
        }
    #pragma unroll
    for (int nt = 0; nt < 4; ++nt)
        #pragma unroll
        for (int r = 0; r < 4; ++r) {
            const int row = w * 16 + quad * 4 + r, col = nt * 16 + m;
            Qtb16[cb + row * 64 + col] = __float2bfloat16(qtacc[nt][r]);
            AMb16[cb + row * 64 + col] = __float2bfloat16(amacc[nt][r]);
            Tb16[cb + row * 64 + col]  = __float2bfloat16(tacc[nt][r]);
            Wb16[cb + row * 64 + col]  = __float2bfloat16(wacc[nt][r]);
        }
}

// ---------------------------------------------------------------------------
// Kernel 4: fused scan — BARRIER-FREE single-wave blocks. 256 blocks x 64
// threads; each wave owns a full 16-col d-stripe: zacc[4] = all 64 s-rows.
// Per chunk (32 MFMAs, 0 barriers):
//   y[t][d]    = Qt Zt + AM Vt ; out = x + y
//   zacc[s][d] += T' Zt + W Vt
//   Zt (LDS, [d][s] bf16) <- zacc, in-wave transpose via 4 ds_write_b64;
//   DS ops are in program order within a wave -> no s_barrier ever.
// V B-frags gathered directly from global ([d][j] pattern, u16 loads).
// ---------------------------------------------------------------------------
__global__ __launch_bounds__(64) void scan2_kernel(
    const bf16* __restrict__ Tb16, const bf16* __restrict__ Wb16,
    const bf16* __restrict__ AMb16, const bf16* __restrict__ Qtb16,
    const bf16* __restrict__ v16, const float* __restrict__ x,
    float* __restrict__ out)
{
    __shared__ bf16 Zt[16][72];           // [d][s], bf16
    const int dblk = blockIdx.x & 63, b = blockIdx.x >> 6;
    const int tid = threadIdx.x;
    const int m = tid & 15, quad = tid >> 4;
    const int d0 = dblk * 16;

    // zero Zt (1152 entries / 64 lanes = 18 each)
    for (int i = tid; i < 16 * 72; i += 64)
        (&Zt[0][0])[i] = __float2bfloat16(0.f);
    // in-wave: LDS ops ordered; compiler inserts lgkmcnt before first read.

    f32x4 zacc[4] = {};

    for (int c = 0; c < NC; ++c) {
        const size_t cb = ((size_t)b * NC + c) * 4096;
        const size_t rowbase = (size_t)b * SS + (size_t)c * 64;

        // ---- global A-frags (b128, contiguous): 4 matrices x 4 mt x 2 ks
        bf16x8 fT[4][2], fW[4][2], fA[4][2], fQ[4][2];
        #pragma unroll
        for (int mt = 0; mt < 4; ++mt)
            #pragma unroll
            for (int ks = 0; ks < 2; ++ks) {
                const size_t off = cb + (mt * 16 + m) * 64 + ks * 32 + quad * 8;
                fT[mt][ks] = *reinterpret_cast<const bf16x8*>(Tb16 + off);
                fW[mt][ks] = *reinterpret_cast<const bf16x8*>(Wb16 + off);
                fA[mt][ks] = *reinterpret_cast<const bf16x8*>(AMb16 + off);
                fQ[mt][ks] = *reinterpret_cast<const bf16x8*>(Qtb16 + off);
            }

        // ---- V B-frags: Vt[d=m][j = ks*32+quad*8+jj] gathered from global
        bf16x8 fV[2];
        #pragma unroll
        for (int ks = 0; ks < 2; ++ks) {
            alignas(16) unsigned short vt[8];
            #pragma unroll
            for (int jj = 0; jj < 8; ++jj)
                vt[jj] = *reinterpret_cast<const unsigned short*>(
                    v16 + (rowbase + ks * 32 + quad * 8 + jj) * DD + d0 + m);
            fV[ks] = *reinterpret_cast<bf16x8*>(vt);
        }

        // ---- x loads (residual), C/D pattern
        float xv[4][4];
        #pragma unroll
        for (int mt = 0; mt < 4; ++mt)
            #pragma unroll
            for (int r = 0; r < 4; ++r)
                xv[mt][r] = x[(rowbase + mt * 16 + quad * 4 + r) * DD + d0 + m];

        // ---- Z B-frags from LDS (written end of previous chunk)
        bf16x8 fZ[2];
        #pragma unroll
        for (int ks = 0; ks < 2; ++ks)
            fZ[ks] = *reinterpret_cast<const bf16x8*>(&Zt[m][ks * 32 + quad * 8]);

        // ---- MFMAs: y then zacc
        f32x4 y[4] = {};
        #pragma unroll
        for (int mt = 0; mt < 4; ++mt) {
            #pragma unroll
            for (int ks = 0; ks < 2; ++ks) {
                y[mt] = __builtin_amdgcn_mfma_f32_16x16x32_bf16(fQ[mt][ks], fZ[ks], y[mt], 0, 0, 0);
                y[mt] = __builtin_amdgcn_mfma_f32_16x16x32_bf16(fA[mt][ks], fV[ks], y[mt], 0, 0, 0);
                zacc[mt] = __builtin_amdgcn_mfma_f32_16x16x32_bf16(fT[mt][ks], fZ[ks], zacc[mt], 0, 0, 0);
                zacc[mt] = __builtin_amdgcn_mfma_f32_16x16x32_bf16(fW[mt][ks], fV[ks], zacc[mt], 0, 0, 0);
            }
        }

        // ---- store out = x + y
        #pragma unroll
        for (int mt = 0; mt < 4; ++mt)
            #pragma unroll
            for (int r = 0; r < 4; ++r)
                out[(rowbase + mt * 16 + quad * 4 + r) * DD + d0 + m] =
                    xv[mt][r] + y[mt][r];

        // ---- write new Z transposed into LDS: Zt[m_d][s]; s contiguous x4
        #pragma unroll
        for (int mt = 0; mt < 4; ++mt) {
            alignas(8) bf16 zb[4];
            #pragma unroll
            for (int r = 0; r < 4; ++r) zb[r] = __float2bfloat16(zacc[mt][r]);
            *reinterpret_cast<uint2*>(&Zt[m][mt * 16 + quad * 4]) =
                *reinterpret_cast<uint2*>(zb);
        }
    }
}

// ---------------------------------------------------------------------------
extern "C" void kernel_launch(void* const* d_in, const int* in_sizes, int n_in,
                              void* d_out, int out_size, void* d_ws, size_t ws_size,
                              hipStream_t stream)
{
    const float* x     = (const float*)d_in[0];
    const float* Wk    = (const float*)d_in[1];
    const float* bk    = (const float*)d_in[2];
    const float* Wv    = (const float*)d_in[3];
    const float* bv    = (const float*)d_in[4];
    const float* Wq    = (const float*)d_in[5];
    const float* bq    = (const float*)d_in[6];
    const float* gamma = (const float*)d_in[7];
    const float* beta  = (const float*)d_in[8];

    char* ws = (char*)d_ws;
    // layout (~38.25 MiB):
    //   [0,16 MiB): hb (bf16, pre->kqv) -- dead after kqv; reused by prep as:
    //     Tb16@0, Qtb16@1MiB, Wb16@2MiB, AMb16@3MiB (1 MiB each)
    //   [16 MiB, +2.25): Wcat (bf16 1152x1024)
    //   +2 MiB: kbuf (fp32)   +2 MiB: qbuf (fp32)
    //   +16 MiB: vbuf16 (bf16 8192x1024)
    const size_t WCAT_B = (size_t)NCAT * DD * 2;   // 2.25 MiB
    bf16*  hb    = (bf16*)ws;
    bf16*  Tb16  = (bf16*)(ws + 0 * MiB);
    bf16*  Qtb16 = (bf16*)(ws + 1 * MiB);
    bf16*  Wb16  = (bf16*)(ws + 2 * MiB);
    bf16*  AMb16 = (bf16*)(ws + 3 * MiB);
    bf16*  Wcat  = (bf16*)(ws + 16 * MiB);
    float* kbuf  = (float*)(ws + 16 * MiB + WCAT_B);
    float* qbuf  = (float*)(ws + 18 * MiB + WCAT_B);
    bf16*  v16   = (bf16*)(ws + 20 * MiB + WCAT_B);

    pre_kernel<<<NCVT + BB * SS, 256, 0, stream>>>(
        Wk, Wq, Wv, Wcat, x, gamma, beta, hb);
    kqv_kernel<<<(NCAT / 128) * (BB * SS / 128), 256, 0, stream>>>(
        hb, Wcat, bk, bq, bv, kbuf, qbuf, v16);
    prep_kernel<<<dim3(NC, BB), 256, 0, stream>>>(
        kbuf, qbuf, Tb16, Wb16, AMb16, Qtb16);
    scan2_kernel<<<64 * BB, 64, 0, stream>>>(
        Tb16, Wb16, AMb16, Qtb16, v16, x, (float*)d_out);
}